// Round 2
// baseline (1700.277 us; speedup 1.0000x reference)
//
#include <hip/hip_runtime.h>
#include <cmath>

// Problem constants
#define NPTS   1000000
#define GXD    116
#define GYD    87
#define NB     4
#define NSEG   40368          // NB*GXD*GYD
#define OUTN   25690112       // 4*128*224*224

// workspace layout in 4-byte elements
#define OFF_INV    0          // NPTS int
#define OFF_SORT   1000000    // NPTS int
#define OFF_CNT    2000000    // NSEG int
#define OFF_OFFS   2050000    // NSEG+1 int
#define OFF_FILL   2100000    // NSEG int
#define OFF_STATS  2150000    // float: [0..14) S-moments, [16..144) sum1, [144..272) ss1
#define OFF_BN0    2150400    // float: [0..32) a0, [32..64) b0'
#define OFF_MINP   2160000    // NSEG*128 float
#define OFF_MAXP   7350000    // NSEG*128 float
#define OFF_DENSE  12550000   // 4*128*87*116 float

__device__ __forceinline__ float fastrcp(float x) { return __builtin_amdgcn_rcpf(x); }
__device__ __forceinline__ float swishf(float z) { return z * fastrcp(1.0f + __expf(-z)); }
__device__ __forceinline__ float bcastf(float v, int l) {
  return __builtin_bit_cast(float, __builtin_amdgcn_readlane(__builtin_bit_cast(int, v), l));
}

__global__ __launch_bounds__(256) void k_init(int* __restrict__ cnt, int* __restrict__ fill,
                                              float* __restrict__ stats) {
  int i = blockIdx.x * 256 + threadIdx.x;
  if (i < NSEG) { cnt[i] = 0; fill[i] = 0; }
  if (i < 400) stats[i] = 0.0f;
}

// Pass 1: inv + cnt + feats moment matrix (S1[4], upper-tri S2[10]).
// Grid-stride with register accumulation so the 14-value butterfly reduction is
// amortized over ~15 points/thread (it was ~170 instr/point in R1).
__global__ __launch_bounds__(256) void k_point1(const float* __restrict__ pts,
                                                int* __restrict__ inv,
                                                int* __restrict__ cnt,
                                                float* __restrict__ Sg) {
  float acc[14];
  #pragma unroll
  for (int q = 0; q < 14; ++q) acc[q] = 0.0f;
  const float i346 = 1.0f / 346.0f, i260 = 1.0f / 260.0f, i200 = 1.0f / 200.0f;
  const int stride = gridDim.x * 256;
  for (int i = blockIdx.x * 256 + threadIdx.x; i < NPTS; i += stride) {
    float b = pts[i*5+0], x = pts[i*5+1], y = pts[i*5+2], t = pts[i*5+3], p = pts[i*5+4];
    // exact IEEE divide here: floor(RN(x/3)) must match jax at cell boundaries
    int cx = (int)floorf(x / 3.0f);
    int cy = (int)floorf(y / 3.0f);
    int bi = (int)b;
    if (cx >= 0 && cx < GXD && cy >= 0 && cy < GYD && bi >= 0 && bi < NB) {
      int iv = (bi*GXD + cx)*GYD + cy;
      inv[i] = iv;
      atomicAdd(&cnt[iv], 1);
    } else {
      inv[i] = -1;
    }
    float f0 = x*i346, f1 = y*i260, f2 = t*i200, f3 = p;
    acc[0]+=f0; acc[1]+=f1; acc[2]+=f2; acc[3]+=f3;
    acc[4]+=f0*f0; acc[5]+=f0*f1; acc[6]+=f0*f2; acc[7]+=f0*f3;
    acc[8]+=f1*f1; acc[9]+=f1*f2; acc[10]+=f1*f3;
    acc[11]+=f2*f2; acc[12]+=f2*f3; acc[13]+=f3*f3;
  }
  __shared__ float lds[4*14];
  int lane = threadIdx.x & 63, wave = threadIdx.x >> 6;
  #pragma unroll
  for (int q = 0; q < 14; ++q) {
    float v = acc[q];
    #pragma unroll
    for (int d = 32; d > 0; d >>= 1) v += __shfl_down(v, d, 64);
    if (lane == 0) lds[wave*14 + q] = v;
  }
  __syncthreads();
  if (threadIdx.x < 14) {
    float v = lds[threadIdx.x] + lds[14+threadIdx.x] + lds[28+threadIdx.x] + lds[42+threadIdx.x];
    atomicAdd(&Sg[threadIdx.x], v);
  }
}

// BN0 coefficients + exclusive scan of cnt -> offs.
// Single block, 1024 threads, 40 segments/thread serial + one shfl scan (was
// a 10-step x 40-tile log-scan with ~80 barriers in R1).
__global__ __launch_bounds__(1024) void k_scan(const int* __restrict__ cnt,
                                               int* __restrict__ offs,
                                               const float* __restrict__ S,
                                               float* __restrict__ bn0,
                                               const float* __restrict__ W0,
                                               const float* __restrict__ g0,
                                               const float* __restrict__ b0) {
  __shared__ int wtot[16];
  const int tid = threadIdx.x;
  if (tid < 32) {
    const float invN = 1.0f / (float)NPTS;
    float w0 = W0[tid], w1 = W0[32+tid], w2 = W0[64+tid], w3 = W0[96+tid];
    float mu = (S[0]*w0 + S[1]*w1 + S[2]*w2 + S[3]*w3) * invN;
    float e2 = (S[4]*w0*w0 + S[8]*w1*w1 + S[11]*w2*w2 + S[13]*w3*w3
              + 2.0f*(S[5]*w0*w1 + S[6]*w0*w2 + S[7]*w0*w3
                    + S[9]*w1*w2 + S[10]*w1*w3 + S[12]*w2*w3)) * invN;
    float var = e2 - mu*mu;
    float a = rsqrtf(var + 1e-3f) * g0[tid];
    bn0[tid] = a;
    bn0[32+tid] = b0[tid] - mu*a;
  }
  const int CH = 40;                      // 1024*40 = 40960 >= NSEG
  const int base = tid * CH;
  int loc[CH];
  int s = 0;
  #pragma unroll
  for (int i = 0; i < CH; ++i) {
    int v = (base + i < NSEG) ? cnt[base + i] : 0;
    loc[i] = s; s += v;
  }
  int inc = s;
  const int lane = tid & 63, wv = tid >> 6;
  #pragma unroll
  for (int d = 1; d < 64; d <<= 1) {
    int t = __shfl_up(inc, d, 64);
    if (lane >= d) inc += t;
  }
  if (lane == 63) wtot[wv] = inc;
  __syncthreads();
  if (tid == 0) {
    int run = 0;
    #pragma unroll
    for (int w = 0; w < 16; ++w) { int t = wtot[w]; wtot[w] = run; run += t; }
    offs[NSEG] = run;
  }
  __syncthreads();
  int ex = wtot[wv] + (inc - s);          // exclusive prefix for this thread
  #pragma unroll
  for (int i = 0; i < CH; ++i)
    if (base + i < NSEG) offs[base + i] = ex + loc[i];
}

// Counting-sort scatter: point ids grouped by segment
__global__ __launch_bounds__(256) void k_scatter(const int* __restrict__ inv,
                                                 const int* __restrict__ offs,
                                                 int* __restrict__ fill,
                                                 int* __restrict__ sortedIdx) {
  int i = blockIdx.x * 256 + threadIdx.x;
  if (i >= NPTS) return;
  int iv = inv[i];
  if (iv < 0) return;
  int pos = offs[iv] + atomicAdd(&fill[iv], 1);
  sortedIdx[pos] = i;
}

// Main segment pass: one wave per segment, SINGLE pass over points.
// pre1 = u + c_s with u = h0 @ W1[0:32] (per point), c_s = m0 @ W1[32:64]
// (per segment). Track per-segment min/max/sum/sumsq of u plus m0-max in the
// same loop; fold c_s at segment end (min/max shift, BN1 stats expansion).
// Lanes 0..31 process even point of a pair, lanes 32..63 the odd point.
__global__ __launch_bounds__(256, 8) void k_seg(const float* __restrict__ pts,
                                                const int* __restrict__ sortedIdx,
                                                const int* __restrict__ offs,
                                                const float* __restrict__ W0,
                                                const float* __restrict__ bn0,
                                                const float* __restrict__ W1g,
                                                float* __restrict__ minp,
                                                float* __restrict__ maxp,
                                                float* __restrict__ stats) {
  __shared__ __align__(16) float w1s[32*128];   // W1 top half (h0 part), 16 KB
  __shared__ float red[4][64][4];               // 4 KB
  const int tid = threadIdx.x;
  for (int i = tid; i < 32*128; i += 256) w1s[i] = W1g[i];
  __syncthreads();
  const int wave = tid >> 6, lane = tid & 63, j = lane & 31, half = lane >> 5;
  const float i346 = 1.0f / 346.0f, i260 = 1.0f / 260.0f, i200 = 1.0f / 200.0f;
  const float w0a = W0[j]*i346, w0b = W0[32+j]*i260, w0c = W0[64+j]*i200, w0d = W0[96+j];
  const float a0 = bn0[j], c0 = bn0[32+j];
  const float2* __restrict__ B2 = (const float2*)(W1g + 32*128);
  float gs0 = 0.f, gs1 = 0.f, gq0 = 0.f, gq1 = 0.f;
  const int nw = gridDim.x * 4;
  for (int s = blockIdx.x*4 + wave; s < NSEG; s += nw) {
    const int off = offs[s];
    const int pend = offs[s+1];
    const int n = pend - off;
    if (n <= 0) continue;
    float mx = -1e30f;
    float mn0 = 1e30f, mn1 = 1e30f, mh0 = -1e30f, mh1 = -1e30f;
    float sac0 = 0.f, sac1 = 0.f, ssc0 = 0.f, ssc1 = 0.f;
    for (int p = off; p < pend; p += 4) {
      // pair A = points p,p+1 ; pair B = points p+2,p+3 (clamped when past end)
      int pa = p + half;     bool vA = pa < pend; if (!vA) pa = off;
      int pb = p + 2 + half; bool vB = pb < pend; if (!vB) pb = off;
      int ia = sortedIdx[pa], ib = sortedIdx[pb];
      const float* qa = pts + ia*5;
      const float* qb = pts + ib*5;
      float preA = qa[1]*w0a + qa[2]*w0b + qa[3]*w0c + qa[4]*w0d;
      float preB = qb[1]*w0a + qb[2]*w0b + qb[3]*w0c + qb[4]*w0d;
      float hA = swishf(fmaf(a0, preA, c0));
      float hB = swishf(fmaf(a0, preB, c0));
      if (vA) mx = fmaxf(mx, hA);
      if (vB) mx = fmaxf(mx, hB);
      float ac00=0.f, ac01=0.f, ac10=0.f, ac11=0.f, ac20=0.f, ac21=0.f, ac30=0.f, ac31=0.f;
      #pragma unroll
      for (int k = 0; k < 32; ++k) {
        const float2 w = *(const float2*)&w1s[k*128 + 2*lane];
        float x0 = bcastf(hA, k);
        float x1 = bcastf(hA, 32 + k);
        float x2 = bcastf(hB, k);
        float x3 = bcastf(hB, 32 + k);
        ac00 = fmaf(x0, w.x, ac00); ac01 = fmaf(x0, w.y, ac01);
        ac10 = fmaf(x1, w.x, ac10); ac11 = fmaf(x1, w.y, ac11);
        ac20 = fmaf(x2, w.x, ac20); ac21 = fmaf(x2, w.y, ac21);
        ac30 = fmaf(x3, w.x, ac30); ac31 = fmaf(x3, w.y, ac31);
      }
      int np = pend - p; if (np > 4) np = 4;
      float a0s[4] = {ac00, ac10, ac20, ac30};
      float a1s[4] = {ac01, ac11, ac21, ac31};
      #pragma unroll
      for (int g = 0; g < 4; ++g) {
        if (g < np) {
          mn0 = fminf(mn0, a0s[g]); mh0 = fmaxf(mh0, a0s[g]);
          mn1 = fminf(mn1, a1s[g]); mh1 = fmaxf(mh1, a1s[g]);
          sac0 += a0s[g]; ssc0 += a0s[g]*a0s[g];
          sac1 += a1s[g]; ssc1 += a1s[g]*a1s[g];
        }
      }
    }
    // segment epilogue: m0 across halves, c_s = m0 @ W1[32:64], fold
    float m0v = fmaxf(mx, __shfl_xor(mx, 32, 64));
    float cA = 0.f, cB = 0.f;
    #pragma unroll
    for (int k = 0; k < 32; ++k) {
      float mk = bcastf(m0v, k);
      float2 w = B2[k*64 + lane];
      cA = fmaf(mk, w.x, cA); cB = fmaf(mk, w.y, cB);
    }
    *(float2*)&minp[s*128 + 2*lane] = make_float2(mn0 + cA, mn1 + cB);
    *(float2*)&maxp[s*128 + 2*lane] = make_float2(mh0 + cA, mh1 + cB);
    float nf = (float)n;
    gs0 += sac0 + nf*cA;
    gs1 += sac1 + nf*cB;
    gq0 += ssc0 + 2.0f*cA*sac0 + nf*cA*cA;
    gq1 += ssc1 + 2.0f*cB*sac1 + nf*cB*cB;
  }
  red[wave][lane][0] = gs0; red[wave][lane][1] = gs1;
  red[wave][lane][2] = gq0; red[wave][lane][3] = gq1;
  __syncthreads();
  if (wave == 0) {
    float t0 = red[0][lane][0] + red[1][lane][0] + red[2][lane][0] + red[3][lane][0];
    float t1 = red[0][lane][1] + red[1][lane][1] + red[2][lane][1] + red[3][lane][1];
    float t2 = red[0][lane][2] + red[1][lane][2] + red[2][lane][2] + red[3][lane][2];
    float t3 = red[0][lane][3] + red[1][lane][3] + red[2][lane][3] + red[3][lane][3];
    atomicAdd(&stats[16 + 2*lane],      t0);
    atomicAdd(&stats[16 + 2*lane + 1],  t1);
    atomicAdd(&stats[144 + 2*lane],     t2);
    atomicAdd(&stats[144 + 2*lane + 1], t3);
  }
}

// Dense grid: BN1 + swish at pre-extremes (exact segment_max via swish
// quasiconvexity), LDS transpose for coalesced writes.
__global__ __launch_bounds__(256) void k_dense(const float* __restrict__ minp,
                                               const float* __restrict__ maxp,
                                               const int* __restrict__ offs,
                                               const float* __restrict__ stats,
                                               const float* __restrict__ g1,
                                               const float* __restrict__ b1,
                                               float* __restrict__ dense) {
  __shared__ float tile[116*129];
  const int b = blockIdx.x / GYD;
  const int gy = blockIdx.x % GYD;
  const int tid = threadIdx.x;
  const float invN = 1.0f / (float)NPTS;
  for (int i = tid; i < 116*128; i += 256) {
    int gx = i >> 7, c = i & 127;
    int s = (b*GXD + gx)*GYD + gy;
    float m = 0.0f;
    if (offs[s+1] - offs[s] > 0) {
      float mu = stats[16+c] * invN;
      float var = stats[144+c] * invN - mu*mu;
      float a = rsqrtf(var + 1e-3f) * g1[c];
      float bb = b1[c] - mu*a;
      float zl = a*minp[s*128+c] + bb;
      float zh = a*maxp[s*128+c] + bb;
      m = fmaxf(swishf(zl), swishf(zh));
    }
    tile[gx*129 + c] = m;
  }
  __syncthreads();
  for (int i = tid; i < 128*116; i += 256) {
    int c = i / 116, gx = i % 116;
    dense[((b*128 + c)*GYD + gy)*GXD + gx] = tile[gx*129 + c];
  }
}

// Bilinear resize (align-corners), dense (4,128,87,116) -> out (4,128,224,224),
// float4 stores (224 = 56*4).
__global__ __launch_bounds__(256) void k_resize(const float* __restrict__ dense,
                                                float* __restrict__ out) {
  int o4 = blockIdx.x * 256 + threadIdx.x;
  if (o4 >= OUTN/4) return;
  int xq = o4 % 56;
  int r = o4 / 56;
  int yo = r % 224;
  int bc = r / 224;
  float ys = (float)yo * (86.0f/223.0f);
  float yf = floorf(ys); int y0 = (int)yf; int y1 = min(y0+1, 86); float wy = ys - yf;
  const float* d0 = dense + bc*(87*116) + y0*116;
  const float* d1 = dense + bc*(87*116) + y1*116;
  float res[4];
  #pragma unroll
  for (int g = 0; g < 4; ++g) {
    int xo = xq*4 + g;
    float xs = (float)xo * (115.0f/223.0f);
    float xf = floorf(xs); int x0 = (int)xf; int x1 = min(x0+1, 115); float wx = xs - xf;
    float c0v = d0[x0]*(1.0f-wy) + d1[x0]*wy;
    float c1v = d0[x1]*(1.0f-wy) + d1[x1]*wy;
    res[g] = c0v*(1.0f-wx) + c1v*wx;
  }
  *(float4*)&out[o4*4] = make_float4(res[0], res[1], res[2], res[3]);
}

extern "C" void kernel_launch(void* const* d_in, const int* in_sizes, int n_in,
                              void* d_out, int out_size, void* d_ws, size_t ws_size,
                              hipStream_t stream) {
  // setup_inputs order: fus(unused), points, W0, g0, b0, W1, g1, b1
  const float* pts = (const float*)d_in[1];
  const float* W0  = (const float*)d_in[2];
  const float* g0  = (const float*)d_in[3];
  const float* b0  = (const float*)d_in[4];
  const float* W1  = (const float*)d_in[5];
  const float* g1  = (const float*)d_in[6];
  const float* b1  = (const float*)d_in[7];
  float* out = (float*)d_out;
  int*   wsi = (int*)d_ws;
  float* wsf = (float*)d_ws;

  k_init<<<158, 256, 0, stream>>>(wsi+OFF_CNT, wsi+OFF_FILL, wsf+OFF_STATS);
  k_point1<<<256, 256, 0, stream>>>(pts, wsi+OFF_INV, wsi+OFF_CNT, wsf+OFF_STATS);
  k_scan<<<1, 1024, 0, stream>>>(wsi+OFF_CNT, wsi+OFF_OFFS, wsf+OFF_STATS, wsf+OFF_BN0, W0, g0, b0);
  k_scatter<<<(NPTS+255)/256, 256, 0, stream>>>(wsi+OFF_INV, wsi+OFF_OFFS, wsi+OFF_FILL, wsi+OFF_SORT);
  k_seg<<<2048, 256, 0, stream>>>(pts, wsi+OFF_SORT, wsi+OFF_OFFS, W0, wsf+OFF_BN0, W1,
                                  wsf+OFF_MINP, wsf+OFF_MAXP, wsf+OFF_STATS);
  k_dense<<<NB*GYD, 256, 0, stream>>>(wsf+OFF_MINP, wsf+OFF_MAXP, wsi+OFF_OFFS, wsf+OFF_STATS,
                                      g1, b1, wsf+OFF_DENSE);
  k_resize<<<OUTN/4/256, 256, 0, stream>>>(wsf+OFF_DENSE, out);
}

// Round 3
// 733.558 us; speedup vs baseline: 2.3178x; 2.3178x over previous
//
#include <hip/hip_runtime.h>
#include <cmath>

// Problem constants
#define NPTS   1000000
#define GXD    116
#define GYD    87
#define NB     4
#define NSEG   40368          // NB*GXD*GYD
#define OUTN   25690112       // 4*128*224*224

// workspace layout in 4-byte elements
#define OFF_INV    0          // NPTS int
#define OFF_SORT   1000000    // NPTS int
#define OFF_CNT    2000000    // NSEG int
#define OFF_OFFS   2050000    // NSEG+1 int
#define OFF_FILL   2100000    // NSEG int
#define OFF_STATS  2150000    // float: [0..14) S-moments, [16..144) sum1, [144..272) ss1
#define OFF_BN0    2150400    // float: [0..32) a0, [32..64) b0'
#define OFF_MINP   2160000    // NSEG*128 float
#define OFF_MAXP   7350000    // NSEG*128 float
#define OFF_DENSE  12550000   // 4*128*87*116 float

__device__ __forceinline__ float fastrcp(float x) { return __builtin_amdgcn_rcpf(x); }
__device__ __forceinline__ float swishf(float z) { return z * fastrcp(1.0f + __expf(-z)); }
__device__ __forceinline__ float bcastf(float v, int l) {
  return __builtin_bit_cast(float, __builtin_amdgcn_readlane(__builtin_bit_cast(int, v), l));
}

__global__ __launch_bounds__(256) void k_init(int* __restrict__ cnt, int* __restrict__ fill,
                                              float* __restrict__ stats) {
  int i = blockIdx.x * 256 + threadIdx.x;
  if (i < NSEG) { cnt[i] = 0; fill[i] = 0; }
  if (i < 400) stats[i] = 0.0f;
}

// Pass 1: inv + cnt + feats moment matrix (S1[4], upper-tri S2[10]).
__global__ __launch_bounds__(256) void k_point1(const float* __restrict__ pts,
                                                int* __restrict__ inv,
                                                int* __restrict__ cnt,
                                                float* __restrict__ Sg) {
  float acc[14];
  #pragma unroll
  for (int q = 0; q < 14; ++q) acc[q] = 0.0f;
  const float i346 = 1.0f / 346.0f, i260 = 1.0f / 260.0f, i200 = 1.0f / 200.0f;
  const int stride = gridDim.x * 256;
  for (int i = blockIdx.x * 256 + threadIdx.x; i < NPTS; i += stride) {
    float b = pts[i*5+0], x = pts[i*5+1], y = pts[i*5+2], t = pts[i*5+3], p = pts[i*5+4];
    // exact IEEE divide here: floor(RN(x/3)) must match jax at cell boundaries
    int cx = (int)floorf(x / 3.0f);
    int cy = (int)floorf(y / 3.0f);
    int bi = (int)b;
    if (cx >= 0 && cx < GXD && cy >= 0 && cy < GYD && bi >= 0 && bi < NB) {
      int iv = (bi*GXD + cx)*GYD + cy;
      inv[i] = iv;
      atomicAdd(&cnt[iv], 1);
    } else {
      inv[i] = -1;
    }
    float f0 = x*i346, f1 = y*i260, f2 = t*i200, f3 = p;
    acc[0]+=f0; acc[1]+=f1; acc[2]+=f2; acc[3]+=f3;
    acc[4]+=f0*f0; acc[5]+=f0*f1; acc[6]+=f0*f2; acc[7]+=f0*f3;
    acc[8]+=f1*f1; acc[9]+=f1*f2; acc[10]+=f1*f3;
    acc[11]+=f2*f2; acc[12]+=f2*f3; acc[13]+=f3*f3;
  }
  __shared__ float lds[4*14];
  int lane = threadIdx.x & 63, wave = threadIdx.x >> 6;
  #pragma unroll
  for (int q = 0; q < 14; ++q) {
    float v = acc[q];
    #pragma unroll
    for (int d = 32; d > 0; d >>= 1) v += __shfl_down(v, d, 64);
    if (lane == 0) lds[wave*14 + q] = v;
  }
  __syncthreads();
  if (threadIdx.x < 14) {
    float v = lds[threadIdx.x] + lds[14+threadIdx.x] + lds[28+threadIdx.x] + lds[42+threadIdx.x];
    atomicAdd(&Sg[threadIdx.x], v);
  }
}

// BN0 coefficients + exclusive scan of cnt -> offs (single block, serial chunks).
__global__ __launch_bounds__(1024) void k_scan(const int* __restrict__ cnt,
                                               int* __restrict__ offs,
                                               const float* __restrict__ S,
                                               float* __restrict__ bn0,
                                               const float* __restrict__ W0,
                                               const float* __restrict__ g0,
                                               const float* __restrict__ b0) {
  __shared__ int wtot[16];
  const int tid = threadIdx.x;
  if (tid < 32) {
    const float invN = 1.0f / (float)NPTS;
    float w0 = W0[tid], w1 = W0[32+tid], w2 = W0[64+tid], w3 = W0[96+tid];
    float mu = (S[0]*w0 + S[1]*w1 + S[2]*w2 + S[3]*w3) * invN;
    float e2 = (S[4]*w0*w0 + S[8]*w1*w1 + S[11]*w2*w2 + S[13]*w3*w3
              + 2.0f*(S[5]*w0*w1 + S[6]*w0*w2 + S[7]*w0*w3
                    + S[9]*w1*w2 + S[10]*w1*w3 + S[12]*w2*w3)) * invN;
    float var = e2 - mu*mu;
    float a = rsqrtf(var + 1e-3f) * g0[tid];
    bn0[tid] = a;
    bn0[32+tid] = b0[tid] - mu*a;
  }
  const int CH = 40;                      // 1024*40 = 40960 >= NSEG
  const int base = tid * CH;
  int loc[CH];
  int s = 0;
  #pragma unroll
  for (int i = 0; i < CH; ++i) {
    int v = (base + i < NSEG) ? cnt[base + i] : 0;
    loc[i] = s; s += v;
  }
  int inc = s;
  const int lane = tid & 63, wv = tid >> 6;
  #pragma unroll
  for (int d = 1; d < 64; d <<= 1) {
    int t = __shfl_up(inc, d, 64);
    if (lane >= d) inc += t;
  }
  if (lane == 63) wtot[wv] = inc;
  __syncthreads();
  if (tid == 0) {
    int run = 0;
    #pragma unroll
    for (int w = 0; w < 16; ++w) { int t = wtot[w]; wtot[w] = run; run += t; }
    offs[NSEG] = run;
  }
  __syncthreads();
  int ex = wtot[wv] + (inc - s);          // exclusive prefix for this thread
  #pragma unroll
  for (int i = 0; i < CH; ++i)
    if (base + i < NSEG) offs[base + i] = ex + loc[i];
}

// Counting-sort scatter: point ids grouped by segment
__global__ __launch_bounds__(256) void k_scatter(const int* __restrict__ inv,
                                                 const int* __restrict__ offs,
                                                 int* __restrict__ fill,
                                                 int* __restrict__ sortedIdx) {
  int i = blockIdx.x * 256 + threadIdx.x;
  if (i >= NPTS) return;
  int iv = inv[i];
  if (iv < 0) return;
  int pos = offs[iv] + atomicAdd(&fill[iv], 1);
  sortedIdx[pos] = i;
}

// Main segment pass: one wave per segment, SINGLE pass over points.
// pre1 = u + c_s with u = h0 @ W1[0:32] (per point), c_s = m0 @ W1[32:64]
// (per segment). NOTE: no min-waves clause in launch_bounds — R2's (256,8)
// capped VGPRs at 32 and spilled ~4.8 GB to scratch (FETCH 67MB->3.7GB).
__global__ __launch_bounds__(256) void k_seg(const float* __restrict__ pts,
                                             const int* __restrict__ sortedIdx,
                                             const int* __restrict__ offs,
                                             const float* __restrict__ W0,
                                             const float* __restrict__ bn0,
                                             const float* __restrict__ W1g,
                                             float* __restrict__ minp,
                                             float* __restrict__ maxp,
                                             float* __restrict__ stats) {
  __shared__ __align__(16) float w1s[32*128];   // W1 top half (h0 part), 16 KB
  __shared__ float red[4][64][4];               // 4 KB
  const int tid = threadIdx.x;
  for (int i = tid; i < 32*128; i += 256) w1s[i] = W1g[i];
  __syncthreads();
  const int wave = tid >> 6, lane = tid & 63, j = lane & 31, half = lane >> 5;
  const float i346 = 1.0f / 346.0f, i260 = 1.0f / 260.0f, i200 = 1.0f / 200.0f;
  const float w0a = W0[j]*i346, w0b = W0[32+j]*i260, w0c = W0[64+j]*i200, w0d = W0[96+j];
  const float a0 = bn0[j], c0 = bn0[32+j];
  const float2* __restrict__ B2 = (const float2*)(W1g + 32*128);
  float gs0 = 0.f, gs1 = 0.f, gq0 = 0.f, gq1 = 0.f;
  const int nw = gridDim.x * 4;
  for (int s = blockIdx.x*4 + wave; s < NSEG; s += nw) {
    const int off = offs[s];
    const int pend = offs[s+1];
    const int n = pend - off;
    if (n <= 0) continue;
    float mx = -1e30f;
    float mn0 = 1e30f, mn1 = 1e30f, mh0 = -1e30f, mh1 = -1e30f;
    float sac0 = 0.f, sac1 = 0.f, ssc0 = 0.f, ssc1 = 0.f;
    for (int p = off; p < pend; p += 4) {
      // pair A = points p,p+1 ; pair B = points p+2,p+3 (clamped when past end)
      int pa = p + half;     bool vA = pa < pend; if (!vA) pa = off;
      int pb = p + 2 + half; bool vB = pb < pend; if (!vB) pb = off;
      int ia = sortedIdx[pa], ib = sortedIdx[pb];
      const float* qa = pts + ia*5;
      const float* qb = pts + ib*5;
      float preA = qa[1]*w0a + qa[2]*w0b + qa[3]*w0c + qa[4]*w0d;
      float preB = qb[1]*w0a + qb[2]*w0b + qb[3]*w0c + qb[4]*w0d;
      float hA = swishf(fmaf(a0, preA, c0));
      float hB = swishf(fmaf(a0, preB, c0));
      if (vA) mx = fmaxf(mx, hA);
      if (vB) mx = fmaxf(mx, hB);
      float ac00=0.f, ac01=0.f, ac10=0.f, ac11=0.f, ac20=0.f, ac21=0.f, ac30=0.f, ac31=0.f;
      #pragma unroll
      for (int k = 0; k < 32; ++k) {
        const float2 w = *(const float2*)&w1s[k*128 + 2*lane];
        float x0 = bcastf(hA, k);
        float x1 = bcastf(hA, 32 + k);
        float x2 = bcastf(hB, k);
        float x3 = bcastf(hB, 32 + k);
        ac00 = fmaf(x0, w.x, ac00); ac01 = fmaf(x0, w.y, ac01);
        ac10 = fmaf(x1, w.x, ac10); ac11 = fmaf(x1, w.y, ac11);
        ac20 = fmaf(x2, w.x, ac20); ac21 = fmaf(x2, w.y, ac21);
        ac30 = fmaf(x3, w.x, ac30); ac31 = fmaf(x3, w.y, ac31);
      }
      int np = pend - p; if (np > 4) np = 4;
      float a0s[4] = {ac00, ac10, ac20, ac30};
      float a1s[4] = {ac01, ac11, ac21, ac31};
      #pragma unroll
      for (int g = 0; g < 4; ++g) {
        if (g < np) {
          mn0 = fminf(mn0, a0s[g]); mh0 = fmaxf(mh0, a0s[g]);
          mn1 = fminf(mn1, a1s[g]); mh1 = fmaxf(mh1, a1s[g]);
          sac0 += a0s[g]; ssc0 += a0s[g]*a0s[g];
          sac1 += a1s[g]; ssc1 += a1s[g]*a1s[g];
        }
      }
    }
    // segment epilogue: m0 across halves, c_s = m0 @ W1[32:64], fold
    float m0v = fmaxf(mx, __shfl_xor(mx, 32, 64));
    float cA = 0.f, cB = 0.f;
    #pragma unroll
    for (int k = 0; k < 32; ++k) {
      float mk = bcastf(m0v, k);
      float2 w = B2[k*64 + lane];
      cA = fmaf(mk, w.x, cA); cB = fmaf(mk, w.y, cB);
    }
    *(float2*)&minp[s*128 + 2*lane] = make_float2(mn0 + cA, mn1 + cB);
    *(float2*)&maxp[s*128 + 2*lane] = make_float2(mh0 + cA, mh1 + cB);
    float nf = (float)n;
    gs0 += sac0 + nf*cA;
    gs1 += sac1 + nf*cB;
    gq0 += ssc0 + 2.0f*cA*sac0 + nf*cA*cA;
    gq1 += ssc1 + 2.0f*cB*sac1 + nf*cB*cB;
  }
  red[wave][lane][0] = gs0; red[wave][lane][1] = gs1;
  red[wave][lane][2] = gq0; red[wave][lane][3] = gq1;
  __syncthreads();
  if (wave == 0) {
    float t0 = red[0][lane][0] + red[1][lane][0] + red[2][lane][0] + red[3][lane][0];
    float t1 = red[0][lane][1] + red[1][lane][1] + red[2][lane][1] + red[3][lane][1];
    float t2 = red[0][lane][2] + red[1][lane][2] + red[2][lane][2] + red[3][lane][2];
    float t3 = red[0][lane][3] + red[1][lane][3] + red[2][lane][3] + red[3][lane][3];
    atomicAdd(&stats[16 + 2*lane],      t0);
    atomicAdd(&stats[16 + 2*lane + 1],  t1);
    atomicAdd(&stats[144 + 2*lane],     t2);
    atomicAdd(&stats[144 + 2*lane + 1], t3);
  }
}

// Dense grid: BN1 + swish at pre-extremes (exact segment_max via swish
// quasiconvexity), LDS transpose for coalesced writes.
__global__ __launch_bounds__(256) void k_dense(const float* __restrict__ minp,
                                               const float* __restrict__ maxp,
                                               const int* __restrict__ offs,
                                               const float* __restrict__ stats,
                                               const float* __restrict__ g1,
                                               const float* __restrict__ b1,
                                               float* __restrict__ dense) {
  __shared__ float tile[116*129];
  const int b = blockIdx.x / GYD;
  const int gy = blockIdx.x % GYD;
  const int tid = threadIdx.x;
  const float invN = 1.0f / (float)NPTS;
  for (int i = tid; i < 116*128; i += 256) {
    int gx = i >> 7, c = i & 127;
    int s = (b*GXD + gx)*GYD + gy;
    float m = 0.0f;
    if (offs[s+1] - offs[s] > 0) {
      float mu = stats[16+c] * invN;
      float var = stats[144+c] * invN - mu*mu;
      float a = rsqrtf(var + 1e-3f) * g1[c];
      float bb = b1[c] - mu*a;
      float zl = a*minp[s*128+c] + bb;
      float zh = a*maxp[s*128+c] + bb;
      m = fmaxf(swishf(zl), swishf(zh));
    }
    tile[gx*129 + c] = m;
  }
  __syncthreads();
  for (int i = tid; i < 128*116; i += 256) {
    int c = i / 116, gx = i % 116;
    dense[((b*128 + c)*GYD + gy)*GXD + gx] = tile[gx*129 + c];
  }
}

// Bilinear resize (align-corners), dense (4,128,87,116) -> out (4,128,224,224),
// float4 stores (224 = 56*4).
__global__ __launch_bounds__(256) void k_resize(const float* __restrict__ dense,
                                                float* __restrict__ out) {
  int o4 = blockIdx.x * 256 + threadIdx.x;
  if (o4 >= OUTN/4) return;
  int xq = o4 % 56;
  int r = o4 / 56;
  int yo = r % 224;
  int bc = r / 224;
  float ys = (float)yo * (86.0f/223.0f);
  float yf = floorf(ys); int y0 = (int)yf; int y1 = min(y0+1, 86); float wy = ys - yf;
  const float* d0 = dense + bc*(87*116) + y0*116;
  const float* d1 = dense + bc*(87*116) + y1*116;
  float res[4];
  #pragma unroll
  for (int g = 0; g < 4; ++g) {
    int xo = xq*4 + g;
    float xs = (float)xo * (115.0f/223.0f);
    float xf = floorf(xs); int x0 = (int)xf; int x1 = min(x0+1, 115); float wx = xs - xf;
    float c0v = d0[x0]*(1.0f-wy) + d1[x0]*wy;
    float c1v = d0[x1]*(1.0f-wy) + d1[x1]*wy;
    res[g] = c0v*(1.0f-wx) + c1v*wx;
  }
  *(float4*)&out[o4*4] = make_float4(res[0], res[1], res[2], res[3]);
}

extern "C" void kernel_launch(void* const* d_in, const int* in_sizes, int n_in,
                              void* d_out, int out_size, void* d_ws, size_t ws_size,
                              hipStream_t stream) {
  // setup_inputs order: fus(unused), points, W0, g0, b0, W1, g1, b1
  const float* pts = (const float*)d_in[1];
  const float* W0  = (const float*)d_in[2];
  const float* g0  = (const float*)d_in[3];
  const float* b0  = (const float*)d_in[4];
  const float* W1  = (const float*)d_in[5];
  const float* g1  = (const float*)d_in[6];
  const float* b1  = (const float*)d_in[7];
  float* out = (float*)d_out;
  int*   wsi = (int*)d_ws;
  float* wsf = (float*)d_ws;

  k_init<<<158, 256, 0, stream>>>(wsi+OFF_CNT, wsi+OFF_FILL, wsf+OFF_STATS);
  k_point1<<<256, 256, 0, stream>>>(pts, wsi+OFF_INV, wsi+OFF_CNT, wsf+OFF_STATS);
  k_scan<<<1, 1024, 0, stream>>>(wsi+OFF_CNT, wsi+OFF_OFFS, wsf+OFF_STATS, wsf+OFF_BN0, W0, g0, b0);
  k_scatter<<<(NPTS+255)/256, 256, 0, stream>>>(wsi+OFF_INV, wsi+OFF_OFFS, wsi+OFF_FILL, wsi+OFF_SORT);
  k_seg<<<2048, 256, 0, stream>>>(pts, wsi+OFF_SORT, wsi+OFF_OFFS, W0, wsf+OFF_BN0, W1,
                                  wsf+OFF_MINP, wsf+OFF_MAXP, wsf+OFF_STATS);
  k_dense<<<NB*GYD, 256, 0, stream>>>(wsf+OFF_MINP, wsf+OFF_MAXP, wsi+OFF_OFFS, wsf+OFF_STATS,
                                      g1, b1, wsf+OFF_DENSE);
  k_resize<<<OUTN/4/256, 256, 0, stream>>>(wsf+OFF_DENSE, out);
}